// Round 5
// baseline (104.017 us; speedup 1.0000x reference)
//
#include <hip/hip_runtime.h>

// Problem constants
#define HW   576      // 24*24 pixels
#define CC   512      // channels
#define PW   30       // padded H/W
#define PPK  1024     // padded p rows (900 real + pad)

typedef float f32x4 __attribute__((ext_vector_type(4)));
typedef short s16x8 __attribute__((ext_vector_type(8)));

__device__ __forceinline__ unsigned short f2bf(float f) {
    unsigned u = __float_as_uint(f);                      // RNE fp32->bf16
    return (unsigned short)((u + 0x7FFFu + ((u >> 16) & 1u)) >> 16);
}
__device__ __forceinline__ float bf2f(unsigned short h) {
    return __uint_as_float((unsigned)h << 16);
}
// reflect-pad row map; p>=900 -> zero row 576 of xT
__device__ __forceinline__ int smapf(int p) {
    if (p >= 900) return 576;
    const int y = p / PW, xw = p - y * PW;
    int iy = y - 3;  iy = (iy < 0) ? -iy : (iy > 23 ? 46 - iy : iy);
    int ix = xw - 3; ix = (ix < 0) ? -ix : (ix > 23 ? 46 - ix : ix);
    return iy * 24 + ix;
}

// Workspace byte offsets (total ~4.85 MB)
#define OFF_QT 0u         // bf16 [8][576][64]
#define OFF_KT 589824u    // bf16 [8][1024][64]
#define OFF_VP 1638400u   // bf16 [8][64][1024]
#define OFF_XT 2686976u   // bf16 [577][512] (row 576 = zeros)
#define OFF_WB 3277824u   // bf16 [3][512][512]

// ---------------------------------------------------------------------------
// Kernel 0: build xT (bf16 transpose of x, LDS-tiled 64x64, + zero row) and
// wb (bf16 copy of Wq/Wk/Wv). grid 457 blocks x 256.
// ---------------------------------------------------------------------------
__global__ __launch_bounds__(256) void cvtT(
    const float* __restrict__ x,
    const float* __restrict__ Wq, const float* __restrict__ Wk,
    const float* __restrict__ Wv,
    unsigned short* __restrict__ xT, unsigned short* __restrict__ wb)
{
    const int b = blockIdx.x, t = threadIdx.x;
    if (b < 72) {                                  // transpose: 9 pix-tiles x 8 chan-tiles
        __shared__ float tile[64][65];             // [chan][pix]; stride 65 -> 2-way free
        const int pt = b % 9, ct = b / 9;
        const int p0 = pt * 64, c0 = ct * 64;
        const int tr = t >> 4, tc4 = (t & 15) * 4;
        #pragma unroll
        for (int cr = 0; cr < 4; ++cr) {
            const int row = cr * 16 + tr;          // chan_local
            const float4 v = *(const float4*)&x[(size_t)(c0 + row) * HW + p0 + tc4];
            tile[row][tc4 + 0] = v.x;
            tile[row][tc4 + 1] = v.y;
            tile[row][tc4 + 2] = v.z;
            tile[row][tc4 + 3] = v.w;
        }
        __syncthreads();
        #pragma unroll
        for (int cr = 0; cr < 4; ++cr) {
            const int prow = cr * 16 + tr;         // pix_local
            ushort4 o;
            o.x = f2bf(tile[tc4 + 0][prow]);
            o.y = f2bf(tile[tc4 + 1][prow]);
            o.z = f2bf(tile[tc4 + 2][prow]);
            o.w = f2bf(tile[tc4 + 3][prow]);
            *(ushort4*)&xT[(size_t)(p0 + prow) * CC + c0 + tc4] = o;
        }
    } else if (b == 72) {                          // zero row 576
        if (t < 128) *(ushort4*)&xT[(size_t)576 * CC + t * 4] = (ushort4){0, 0, 0, 0};
    } else {                                       // W convert: 384 blocks x 2048 elems
        const int wi = (b - 73) * 2048 + t * 8;
        const int sel = wi >> 18, off = wi & 262143;
        const float* src = (sel == 0) ? Wq : (sel == 1) ? Wk : Wv;
        const float4 v0 = *(const float4*)&src[off];
        const float4 v1 = *(const float4*)&src[off + 4];
        ushort4 o0, o1;
        o0.x = f2bf(v0.x); o0.y = f2bf(v0.y); o0.z = f2bf(v0.z); o0.w = f2bf(v0.w);
        o1.x = f2bf(v1.x); o1.y = f2bf(v1.y); o1.z = f2bf(v1.z); o1.w = f2bf(v1.w);
        *(ushort4*)&wb[wi]     = o0;
        *(ushort4*)&wb[wi + 4] = o1;
    }
}

// ---------------------------------------------------------------------------
// Kernel 1: Q/K/V projections, K-split MFMA. One BLOCK = one 32x32 output
// tile; the block's 4 waves each cover K-range [w*128, w*128+128), then a
// one-barrier LDS f32x4 reduce: wave w sums and stores 16x16 sub-tile w.
// 1312 blocks x 256 = 5248 waves (~5.1/SIMD) to hide L2 load latency.
// ---------------------------------------------------------------------------
__global__ __launch_bounds__(256) void qkv_ks(
    const unsigned short* __restrict__ xT, const unsigned short* __restrict__ wb,
    const float* __restrict__ bq, const float* __restrict__ bk,
    const float* __restrict__ bv,
    unsigned short* __restrict__ qT, unsigned short* __restrict__ kT,
    unsigned short* __restrict__ vP)
{
    const int b = blockIdx.x;
    const int t = threadIdx.x;
    const int lane = t & 63, w = t >> 6;
    const int fr = lane & 15, u = lane >> 4;

    int sel, m0, n0;
    if (b < 288)      { sel = 0; m0 = (b >> 4) << 5;               n0 = (b & 15) << 5; }
    else if (b < 800) { const int k = b - 288; sel = 1; m0 = (k >> 4) << 5; n0 = (k & 15) << 5; }
    else              { const int k = b - 800; sel = 2; m0 = (k >> 5) << 5; n0 = (k & 31) << 5; }

    const unsigned short *A, *B;
    int ar0, ar1, bn0, bn1;
    if (sel == 0)      { A = xT;          B = wb;
                         ar0 = m0 + fr;         ar1 = m0 + 16 + fr;
                         bn0 = n0 + fr;         bn1 = n0 + 16 + fr; }
    else if (sel == 1) { A = xT;          B = wb + 262144;
                         ar0 = smapf(m0 + fr);  ar1 = smapf(m0 + 16 + fr);
                         bn0 = n0 + fr;         bn1 = n0 + 16 + fr; }
    else               { A = wb + 524288; B = xT;
                         ar0 = m0 + fr;         ar1 = m0 + 16 + fr;
                         bn0 = smapf(n0 + fr);  bn1 = smapf(n0 + 16 + fr); }

    const int kw = w * 128;                       // this wave's K-range
    const unsigned short* Ap0 = A + (size_t)ar0 * CC + kw + u * 8;
    const unsigned short* Ap1 = A + (size_t)ar1 * CC + kw + u * 8;
    const unsigned short* Bp0 = B + (size_t)bn0 * CC + kw + u * 8;
    const unsigned short* Bp1 = B + (size_t)bn1 * CC + kw + u * 8;

    f32x4 acc00 = (f32x4){0.f, 0.f, 0.f, 0.f};
    f32x4 acc01 = (f32x4){0.f, 0.f, 0.f, 0.f};
    f32x4 acc10 = (f32x4){0.f, 0.f, 0.f, 0.f};
    f32x4 acc11 = (f32x4){0.f, 0.f, 0.f, 0.f};
    #pragma unroll
    for (int k0 = 0; k0 < 128; k0 += 32) {
        const s16x8 a0 = *(const s16x8*)(Ap0 + k0);
        const s16x8 a1 = *(const s16x8*)(Ap1 + k0);
        const s16x8 b0 = *(const s16x8*)(Bp0 + k0);
        const s16x8 b1 = *(const s16x8*)(Bp1 + k0);
        acc00 = __builtin_amdgcn_mfma_f32_16x16x32_bf16(a0, b0, acc00, 0, 0, 0);
        acc01 = __builtin_amdgcn_mfma_f32_16x16x32_bf16(a0, b1, acc01, 0, 0, 0);
        acc10 = __builtin_amdgcn_mfma_f32_16x16x32_bf16(a1, b0, acc10, 0, 0, 0);
        acc11 = __builtin_amdgcn_mfma_f32_16x16x32_bf16(a1, b1, acc11, 0, 0, 0);
    }

    // cross-wave K-reduce in LDS; wave w owns sub-tile (mi=w>>1, ni=w&1)
    __shared__ __align__(16) f32x4 red[4][4][64];  // [wave][subtile][lane]
    red[w][0][lane] = acc00;
    red[w][1][lane] = acc01;
    red[w][2][lane] = acc10;
    red[w][3][lane] = acc11;
    __syncthreads();

    f32x4 v = red[0][w][lane];
    #pragma unroll
    for (int w2 = 1; w2 < 4; ++w2) v = v + red[w2][w][lane];

    // epilogue: C/D layout col(fr)=n, row(u*4+r)=m (within 16x16 sub-tile)
    const int mi = w >> 1, ni = w & 1;
    const int n = n0 + ni * 16 + fr;
    #pragma unroll
    for (int r = 0; r < 4; ++r) {
        const int m = m0 + mi * 16 + u * 4 + r;
        if (sel == 0) {
            qT[((size_t)(n >> 6) * HW + m) * 64 + (n & 63)] = f2bf(v[r] + bq[n]);
        } else if (sel == 1) {
            kT[((size_t)(n >> 6) * PPK + m) * 64 + (n & 63)] = f2bf(v[r] + bk[n]);
        } else {
            vP[((size_t)(m >> 6) * 64 + (m & 63)) * PPK + n] = f2bf(v[r] + bv[m]);
        }
    }
}

// ---------------------------------------------------------------------------
// Kernel 2: single-pass MFMA attention + epilogue, 16 waves. Block = (16q,
// head); grid (36, 8) = 288 blocks x 1024 threads. QK: wave w owns p-slice
// [w*64, w*64+64) (4 E^T tiles, e[4]); all 1024 p of bf16 weights in LDS.
// Softmax max/sum reduce across waves via LDS + __syncthreads only (no
// cross-block traffic / fences — R1 post-mortem). PV: wave w owns (d-tile
// w&3, p-quarter w>>2); quarters combined via 12 KB LDS reduce. Block
// writes out = gamma*O/l + x directly. 16 waves -> 4 waves/SIMD on
// single-block CUs (8 on the 32 double-block CUs) vs 2 for the 8-wave
// version: R4 proved all kernels here are latency-bound, so wave count is
// the lever.
// ---------------------------------------------------------------------------
#define WLS 1040      // Wl row stride (shorts); bank step 8 -> verified pattern
__global__ __launch_bounds__(1024) void attn6(
    const unsigned short* __restrict__ qT, const unsigned short* __restrict__ kT,
    const unsigned short* __restrict__ vP, const float* __restrict__ x,
    const float* __restrict__ gamma, float* __restrict__ out)
{
    const int q0 = blockIdx.x * 16;
    const int hd = blockIdx.y;
    const int t  = threadIdx.x;
    const int lane = t & 63, w = t >> 6;          // w in [0,16)
    const int fr = lane & 15, u = lane >> 4;

    __shared__ float cnt_s[PPK];                  // multiplicity table (0 for pads)
    __shared__ __align__(16) unsigned short Wl[16 * WLS];  // weights [q][1024p]
    __shared__ float mw[256], lw[256], sca[16];
    __shared__ __align__(16) f32x4 red[3][4][64]; // PV p-quarter partials

    {                                             // cnt(y)*cnt(x), 0 for pads; 1:1
        const int i = t;
        float c = 0.f;
        if (i < 900) {
            const int y = i / PW, xw = i - y * PW;
            int cy = y + 1;  if (PW - y  < cy) cy = PW - y;  if (cy > 7) cy = 7;
            int cx = xw + 1; if (PW - xw < cx) cx = PW - xw; if (cx > 7) cx = 7;
            c = (float)(cy * cx);
        }
        cnt_s[i] = c;                             // wave w reads only its own
    }                                             // lanes' entries -> no barrier

    // q B-frags (shared across this wave's p-tiles)
    const unsigned short* qrow = qT + ((size_t)hd * HW + q0 + fr) * 64 + u * 8;
    const s16x8 b0 = *(const s16x8*)qrow;
    const s16x8 b1 = *(const s16x8*)(qrow + 32);

    // QK: 4 E^T tiles (16p x 16q) per wave -> this wave's 64 p
    f32x4 e[4];
    #pragma unroll
    for (int t4 = 0; t4 < 4; ++t4) {
        const unsigned short* krow =
            kT + ((size_t)hd * PPK + w * 64 + t4 * 16 + fr) * 64 + u * 8;
        const s16x8 a0 = *(const s16x8*)krow;
        const s16x8 a1 = *(const s16x8*)(krow + 32);
        f32x4 a = (f32x4){0.f, 0.f, 0.f, 0.f};
        a = __builtin_amdgcn_mfma_f32_16x16x32_bf16(a0, b0, a, 0, 0, 0);
        a = __builtin_amdgcn_mfma_f32_16x16x32_bf16(a1, b1, a, 0, 0, 0);
        e[t4] = a;
    }

    // per-q max over this wave's 64 p (regs share q = fr; cross-quad shuffles)
    float m = -1e30f;
    #pragma unroll
    for (int t4 = 0; t4 < 4; ++t4)
        #pragma unroll
        for (int r = 0; r < 4; ++r) m = fmaxf(m, e[t4][r]);
    m = fmaxf(m, __shfl_xor(m, 16));
    m = fmaxf(m, __shfl_xor(m, 32));
    if (lane < 16) mw[w * 16 + lane] = m;
    __syncthreads();                              // mw complete
    float mq = mw[fr];
    #pragma unroll
    for (int j = 1; j < 16; ++j) mq = fmaxf(mq, mw[j * 16 + fr]);

    // weights = cnt * exp(e - mq): bf16 into Wl; per-q partial sums
    float sum = 0.f;
    #pragma unroll
    for (int t4 = 0; t4 < 4; ++t4) {
        const float4 c4 = *(const float4*)&cnt_s[w * 64 + t4 * 16 + u * 4];
        const float cw[4] = {c4.x, c4.y, c4.z, c4.w};
        unsigned short wb4[4];
        #pragma unroll
        for (int r = 0; r < 4; ++r) {
            const float wv2 = cw[r] * __expf(e[t4][r] - mq);
            sum += wv2;
            wb4[r] = f2bf(wv2);
        }
        const int ho = fr * WLS + w * 64 + t4 * 16 + u * 4;
        *(unsigned*)&Wl[ho]     = (unsigned)wb4[0] | ((unsigned)wb4[1] << 16);
        *(unsigned*)&Wl[ho + 2] = (unsigned)wb4[2] | ((unsigned)wb4[3] << 16);
    }
    sum += __shfl_xor(sum, 16);
    sum += __shfl_xor(sum, 32);
    if (lane < 16) lw[w * 16 + lane] = sum;
    __syncthreads();                              // Wl + lw complete

    if (t < 16) {                                 // per-q scale = gamma / l
        float lq = 0.f;
        #pragma unroll
        for (int j = 0; j < 16; ++j) lq += lw[j * 16 + t];
        sca[t] = gamma[0] / lq;
    }

    // PV: wave w owns (d-tile w&3, p-quarter w>>2); O[16q][16d] over 256 p
    const int dt = w & 3, ph = w >> 2;
    f32x4 o = (f32x4){0.f, 0.f, 0.f, 0.f};
    const unsigned short* vrow =
        vP + ((size_t)hd * 64 + dt * 16 + fr) * PPK + ph * 256 + u * 8;
    #pragma unroll
    for (int c = 0; c < 8; ++c) {
        const s16x8 aw = *(const s16x8*)&Wl[fr * WLS + ph * 256 + c * 32 + u * 8];
        const s16x8 bv2 = *(const s16x8*)(vrow + c * 32);
        o = __builtin_amdgcn_mfma_f32_16x16x32_bf16(aw, bv2, o, 0, 0, 0);
    }
    if (ph > 0) red[ph - 1][dt][lane] = o;
    __syncthreads();                              // red + sca ready
    if (ph > 0) return;

    // epilogue: C layout row=q (u*4+r), col=d (dt*16+fr); each lane stores a
    // float4 run of 4 consecutive q at row d -> 16B coalesced segments.
    #pragma unroll
    for (int j = 0; j < 3; ++j) o = o + red[j][dt][lane];
    const int d = hd * 64 + dt * 16 + fr;
    const size_t gb = (size_t)d * HW + q0 + u * 4;
    const float4 x4 = *(const float4*)&x[gb];
    float4 o4;
    o4.x = fmaf(sca[u * 4 + 0], o[0], x4.x);
    o4.y = fmaf(sca[u * 4 + 1], o[1], x4.y);
    o4.z = fmaf(sca[u * 4 + 2], o[2], x4.z);
    o4.w = fmaf(sca[u * 4 + 3], o[3], x4.w);
    *(float4*)&out[gb] = o4;
}

// ---------------------------------------------------------------------------
extern "C" void kernel_launch(void* const* d_in, const int* in_sizes, int n_in,
                              void* d_out, int out_size, void* d_ws, size_t ws_size,
                              hipStream_t stream) {
    const float* x     = (const float*)d_in[0];
    const float* Wq    = (const float*)d_in[1];
    const float* bq    = (const float*)d_in[2];
    const float* Wk    = (const float*)d_in[3];
    const float* bk    = (const float*)d_in[4];
    const float* Wv    = (const float*)d_in[5];
    const float* bv    = (const float*)d_in[6];
    const float* gamma = (const float*)d_in[7];
    float* out = (float*)d_out;

    char* wsb = (char*)d_ws;
    unsigned short* qT = (unsigned short*)(wsb + OFF_QT);
    unsigned short* kT = (unsigned short*)(wsb + OFF_KT);
    unsigned short* vP = (unsigned short*)(wsb + OFF_VP);
    unsigned short* xT = (unsigned short*)(wsb + OFF_XT);
    unsigned short* wb = (unsigned short*)(wsb + OFF_WB);

    cvtT<<<dim3(457), 256, 0, stream>>>(x, Wq, Wk, Wv, xT, wb);
    qkv_ks<<<dim3(1312), 256, 0, stream>>>(xT, wb, bq, bk, bv, qT, kT, vP);
    attn6<<<dim3(36, 8), 1024, 0, stream>>>(qT, kT, vP, x, gamma, out);
}

// Round 6
// 102.955 us; speedup vs baseline: 1.0103x; 1.0103x over previous
//
#include <hip/hip_runtime.h>

// Problem constants
#define HW   576      // 24*24 pixels
#define CC   512      // channels
#define PW   30       // padded H/W
#define PPK  1024     // padded p rows (900 real + pad)

typedef float f32x4 __attribute__((ext_vector_type(4)));
typedef short s16x8 __attribute__((ext_vector_type(8)));

__device__ __forceinline__ unsigned short f2bf(float f) {
    unsigned u = __float_as_uint(f);                      // RNE fp32->bf16
    return (unsigned short)((u + 0x7FFFu + ((u >> 16) & 1u)) >> 16);
}
__device__ __forceinline__ float bf2f(unsigned short h) {
    return __uint_as_float((unsigned)h << 16);
}
// reflect-pad row map; p>=900 -> zero row 576 of xT
__device__ __forceinline__ int smapf(int p) {
    if (p >= 900) return 576;
    const int y = p / PW, xw = p - y * PW;
    int iy = y - 3;  iy = (iy < 0) ? -iy : (iy > 23 ? 46 - iy : iy);
    int ix = xw - 3; ix = (ix < 0) ? -ix : (ix > 23 ? 46 - ix : ix);
    return iy * 24 + ix;
}

// Workspace byte offsets (total ~4.85 MB)
#define OFF_QT 0u         // bf16 [8][576][64]
#define OFF_KT 589824u    // bf16 [8][1024][64]
#define OFF_VP 1638400u   // bf16 [8][64][1024]
#define OFF_XT 2686976u   // bf16 [577][512] (row 576 = zeros)
#define OFF_WB 3277824u   // bf16 [3][512][512]

// ---------------------------------------------------------------------------
// Kernel 0: build xT (bf16 transpose of x, LDS-tiled 64x64, + zero row) and
// wb (bf16 copy of Wq/Wk/Wv). grid 457 blocks x 256.
// ---------------------------------------------------------------------------
__global__ __launch_bounds__(256) void cvtT(
    const float* __restrict__ x,
    const float* __restrict__ Wq, const float* __restrict__ Wk,
    const float* __restrict__ Wv,
    unsigned short* __restrict__ xT, unsigned short* __restrict__ wb)
{
    const int b = blockIdx.x, t = threadIdx.x;
    if (b < 72) {                                  // transpose: 9 pix-tiles x 8 chan-tiles
        __shared__ float tile[64][65];             // [chan][pix]; stride 65 -> 2-way free
        const int pt = b % 9, ct = b / 9;
        const int p0 = pt * 64, c0 = ct * 64;
        const int tr = t >> 4, tc4 = (t & 15) * 4;
        #pragma unroll
        for (int cr = 0; cr < 4; ++cr) {
            const int row = cr * 16 + tr;          // chan_local
            const float4 v = *(const float4*)&x[(size_t)(c0 + row) * HW + p0 + tc4];
            tile[row][tc4 + 0] = v.x;
            tile[row][tc4 + 1] = v.y;
            tile[row][tc4 + 2] = v.z;
            tile[row][tc4 + 3] = v.w;
        }
        __syncthreads();
        #pragma unroll
        for (int cr = 0; cr < 4; ++cr) {
            const int prow = cr * 16 + tr;         // pix_local
            ushort4 o;
            o.x = f2bf(tile[tc4 + 0][prow]);
            o.y = f2bf(tile[tc4 + 1][prow]);
            o.z = f2bf(tile[tc4 + 2][prow]);
            o.w = f2bf(tile[tc4 + 3][prow]);
            *(ushort4*)&xT[(size_t)(p0 + prow) * CC + c0 + tc4] = o;
        }
    } else if (b == 72) {                          // zero row 576
        if (t < 128) *(ushort4*)&xT[(size_t)576 * CC + t * 4] = (ushort4){0, 0, 0, 0};
    } else {                                       // W convert: 384 blocks x 2048 elems
        const int wi = (b - 73) * 2048 + t * 8;
        const int sel = wi >> 18, off = wi & 262143;
        const float* src = (sel == 0) ? Wq : (sel == 1) ? Wk : Wv;
        const float4 v0 = *(const float4*)&src[off];
        const float4 v1 = *(const float4*)&src[off + 4];
        ushort4 o0, o1;
        o0.x = f2bf(v0.x); o0.y = f2bf(v0.y); o0.z = f2bf(v0.z); o0.w = f2bf(v0.w);
        o1.x = f2bf(v1.x); o1.y = f2bf(v1.y); o1.z = f2bf(v1.z); o1.w = f2bf(v1.w);
        *(ushort4*)&wb[wi]     = o0;
        *(ushort4*)&wb[wi + 4] = o1;
    }
}

// ---------------------------------------------------------------------------
// Kernel 1: Q/K/V projections, K-split MFMA. One BLOCK = one 32x32 output
// tile; the block's 4 waves each cover K-range [w*128, w*128+128), then a
// one-barrier LDS f32x4 reduce: wave w sums and stores 16x16 sub-tile w.
// 1312 blocks x 256 = 5248 waves (~5.1/SIMD) to hide L2 load latency.
// ---------------------------------------------------------------------------
__global__ __launch_bounds__(256) void qkv_ks(
    const unsigned short* __restrict__ xT, const unsigned short* __restrict__ wb,
    const float* __restrict__ bq, const float* __restrict__ bk,
    const float* __restrict__ bv,
    unsigned short* __restrict__ qT, unsigned short* __restrict__ kT,
    unsigned short* __restrict__ vP)
{
    const int b = blockIdx.x;
    const int t = threadIdx.x;
    const int lane = t & 63, w = t >> 6;
    const int fr = lane & 15, u = lane >> 4;

    int sel, m0, n0;
    if (b < 288)      { sel = 0; m0 = (b >> 4) << 5;               n0 = (b & 15) << 5; }
    else if (b < 800) { const int k = b - 288; sel = 1; m0 = (k >> 4) << 5; n0 = (k & 15) << 5; }
    else              { const int k = b - 800; sel = 2; m0 = (k >> 5) << 5; n0 = (k & 31) << 5; }

    const unsigned short *A, *B;
    int ar0, ar1, bn0, bn1;
    if (sel == 0)      { A = xT;          B = wb;
                         ar0 = m0 + fr;         ar1 = m0 + 16 + fr;
                         bn0 = n0 + fr;         bn1 = n0 + 16 + fr; }
    else if (sel == 1) { A = xT;          B = wb + 262144;
                         ar0 = smapf(m0 + fr);  ar1 = smapf(m0 + 16 + fr);
                         bn0 = n0 + fr;         bn1 = n0 + 16 + fr; }
    else               { A = wb + 524288; B = xT;
                         ar0 = m0 + fr;         ar1 = m0 + 16 + fr;
                         bn0 = smapf(n0 + fr);  bn1 = smapf(n0 + 16 + fr); }

    const int kw = w * 128;                       // this wave's K-range
    const unsigned short* Ap0 = A + (size_t)ar0 * CC + kw + u * 8;
    const unsigned short* Ap1 = A + (size_t)ar1 * CC + kw + u * 8;
    const unsigned short* Bp0 = B + (size_t)bn0 * CC + kw + u * 8;
    const unsigned short* Bp1 = B + (size_t)bn1 * CC + kw + u * 8;

    f32x4 acc00 = (f32x4){0.f, 0.f, 0.f, 0.f};
    f32x4 acc01 = (f32x4){0.f, 0.f, 0.f, 0.f};
    f32x4 acc10 = (f32x4){0.f, 0.f, 0.f, 0.f};
    f32x4 acc11 = (f32x4){0.f, 0.f, 0.f, 0.f};
    #pragma unroll
    for (int k0 = 0; k0 < 128; k0 += 32) {
        const s16x8 a0 = *(const s16x8*)(Ap0 + k0);
        const s16x8 a1 = *(const s16x8*)(Ap1 + k0);
        const s16x8 b0 = *(const s16x8*)(Bp0 + k0);
        const s16x8 b1 = *(const s16x8*)(Bp1 + k0);
        acc00 = __builtin_amdgcn_mfma_f32_16x16x32_bf16(a0, b0, acc00, 0, 0, 0);
        acc01 = __builtin_amdgcn_mfma_f32_16x16x32_bf16(a0, b1, acc01, 0, 0, 0);
        acc10 = __builtin_amdgcn_mfma_f32_16x16x32_bf16(a1, b0, acc10, 0, 0, 0);
        acc11 = __builtin_amdgcn_mfma_f32_16x16x32_bf16(a1, b1, acc11, 0, 0, 0);
    }

    // cross-wave K-reduce in LDS; wave w owns sub-tile (mi=w>>1, ni=w&1)
    __shared__ __align__(16) f32x4 red[4][4][64];  // [wave][subtile][lane]
    red[w][0][lane] = acc00;
    red[w][1][lane] = acc01;
    red[w][2][lane] = acc10;
    red[w][3][lane] = acc11;
    __syncthreads();

    f32x4 v = red[0][w][lane];
    #pragma unroll
    for (int w2 = 1; w2 < 4; ++w2) v = v + red[w2][w][lane];

    // epilogue: C/D layout col(fr)=n, row(u*4+r)=m (within 16x16 sub-tile)
    const int mi = w >> 1, ni = w & 1;
    const int n = n0 + ni * 16 + fr;
    #pragma unroll
    for (int r = 0; r < 4; ++r) {
        const int m = m0 + mi * 16 + u * 4 + r;
        if (sel == 0) {
            qT[((size_t)(n >> 6) * HW + m) * 64 + (n & 63)] = f2bf(v[r] + bq[n]);
        } else if (sel == 1) {
            kT[((size_t)(n >> 6) * PPK + m) * 64 + (n & 63)] = f2bf(v[r] + bk[n]);
        } else {
            vP[((size_t)(m >> 6) * 64 + (m & 63)) * PPK + n] = f2bf(v[r] + bv[m]);
        }
    }
}

// ---------------------------------------------------------------------------
// Kernel 2: single-pass MFMA attention + epilogue, 8 waves, NO-MAX softmax.
// Block = (16q, head); grid (36, 8) = 288 blocks x 512 threads.
// Energies are bounded (|e| < ~10 << 88): exp never overflows, and the
// constant-shift invariance of softmax means skipping max-subtraction is
// mathematically identical after O/l normalization. This removes the max
// reduce, the mw LDS round, and one of three barriers: QK flows straight
// into weight generation. Each wave fills its OWN cnt_s slice (no barrier
// needed before use). PV: wave w owns (d-tile w&3, p-half w>>2) with
// even/odd dual accumulators (2x8 dependent chains instead of 1x16);
// p-halves combined via small LDS reduce. Block writes out = gamma*O/l + x.
// No cross-block traffic / fences (R1 post-mortem).
// ---------------------------------------------------------------------------
#define WLS 1040      // Wl row stride (shorts); bank step 8 -> verified pattern
__global__ __launch_bounds__(512) void attn7(
    const unsigned short* __restrict__ qT, const unsigned short* __restrict__ kT,
    const unsigned short* __restrict__ vP, const float* __restrict__ x,
    const float* __restrict__ gamma, float* __restrict__ out)
{
    const int q0 = blockIdx.x * 16;
    const int hd = blockIdx.y;
    const int t  = threadIdx.x;
    const int lane = t & 63, w = t >> 6;          // w in [0,8)
    const int fr = lane & 15, u = lane >> 4;

    __shared__ float cnt_s[PPK];                  // multiplicity table (0 for pads)
    __shared__ __align__(16) unsigned short Wl[16 * WLS];  // weights [q][1024p]
    __shared__ float lw[128], sca[16];
    __shared__ float4 red[4][64];                 // PV p-half partials

    // wave-local cnt fill: wave w writes (and later reads) ONLY its own
    // 128-entry slice -> no barrier between fill and use.
    #pragma unroll
    for (int j = 0; j < 2; ++j) {
        const int i = w * 128 + j * 64 + lane;
        float c = 0.f;
        if (i < 900) {
            const int y = i / PW, xw = i - y * PW;
            int cy = y + 1;  if (PW - y  < cy) cy = PW - y;  if (cy > 7) cy = 7;
            int cx = xw + 1; if (PW - xw < cx) cx = PW - xw; if (cx > 7) cx = 7;
            c = (float)(cy * cx);
        }
        cnt_s[i] = c;
    }

    // q B-frags (shared across this wave's p-tiles)
    const unsigned short* qrow = qT + ((size_t)hd * HW + q0 + fr) * 64 + u * 8;
    const s16x8 b0 = *(const s16x8*)qrow;
    const s16x8 b1 = *(const s16x8*)(qrow + 32);

    // QK: 8 E^T tiles (16p x 16q) per wave -> this wave's 128 p
    f32x4 e[8];
    #pragma unroll
    for (int t4 = 0; t4 < 8; ++t4) {
        const unsigned short* krow =
            kT + ((size_t)hd * PPK + w * 128 + t4 * 16 + fr) * 64 + u * 8;
        const s16x8 a0 = *(const s16x8*)krow;
        const s16x8 a1 = *(const s16x8*)(krow + 32);
        f32x4 a = (f32x4){0.f, 0.f, 0.f, 0.f};
        a = __builtin_amdgcn_mfma_f32_16x16x32_bf16(a0, b0, a, 0, 0, 0);
        a = __builtin_amdgcn_mfma_f32_16x16x32_bf16(a1, b1, a, 0, 0, 0);
        e[t4] = a;
    }

    // weights = cnt * exp(e) (no max shift — bounded energies); bf16 into Wl
    float sum = 0.f;
    #pragma unroll
    for (int t4 = 0; t4 < 8; ++t4) {
        const float4 c4 = *(const float4*)&cnt_s[w * 128 + t4 * 16 + u * 4];
        const float cw[4] = {c4.x, c4.y, c4.z, c4.w};
        unsigned short wb4[4];
        #pragma unroll
        for (int r = 0; r < 4; ++r) {
            const float wv2 = cw[r] * __expf(e[t4][r]);
            sum += wv2;
            wb4[r] = f2bf(wv2);
        }
        const int ho = fr * WLS + w * 128 + t4 * 16 + u * 4;
        *(unsigned*)&Wl[ho]     = (unsigned)wb4[0] | ((unsigned)wb4[1] << 16);
        *(unsigned*)&Wl[ho + 2] = (unsigned)wb4[2] | ((unsigned)wb4[3] << 16);
    }
    sum += __shfl_xor(sum, 16);
    sum += __shfl_xor(sum, 32);
    if (lane < 16) lw[w * 16 + lane] = sum;
    __syncthreads();                              // Wl + lw complete

    if (t < 16) {                                 // per-q scale = gamma / l
        float lq = 0.f;
        #pragma unroll
        for (int j = 0; j < 8; ++j) lq += lw[j * 16 + t];
        sca[t] = gamma[0] / lq;
    }

    // PV: wave w owns (d-tile w&3, p-half w>>2); O[16q][16d] over 512 p.
    // Dual accumulators break the 16-long dependent MFMA chain into 2x8.
    const int dt = w & 3, ph = w >> 2;
    f32x4 oA = (f32x4){0.f, 0.f, 0.f, 0.f};
    f32x4 oB = (f32x4){0.f, 0.f, 0.f, 0.f};
    const unsigned short* vrow =
        vP + ((size_t)hd * 64 + dt * 16 + fr) * PPK + ph * 512 + u * 8;
    const unsigned short* wrow = &Wl[fr * WLS + ph * 512 + u * 8];
    #pragma unroll
    for (int c = 0; c < 8; ++c) {
        const s16x8 awA = *(const s16x8*)(wrow + c * 64);
        const s16x8 bvA = *(const s16x8*)(vrow + c * 64);
        const s16x8 awB = *(const s16x8*)(wrow + c * 64 + 32);
        const s16x8 bvB = *(const s16x8*)(vrow + c * 64 + 32);
        oA = __builtin_amdgcn_mfma_f32_16x16x32_bf16(awA, bvA, oA, 0, 0, 0);
        oB = __builtin_amdgcn_mfma_f32_16x16x32_bf16(awB, bvB, oB, 0, 0, 0);
    }
    const f32x4 o = oA + oB;
    if (w >= 4) red[dt][lane] = (float4){o[0], o[1], o[2], o[3]};
    __syncthreads();                              // red + sca ready
    if (w >= 4) return;

    // epilogue: C layout row=q (u*4+r), col=d (dt*16+fr); each lane stores a
    // float4 run of 4 consecutive q at row d -> 16B coalesced segments.
    const float4 r2 = red[dt][lane];
    const int d = hd * 64 + dt * 16 + fr;
    const size_t gb = (size_t)d * HW + q0 + u * 4;
    const float4 x4 = *(const float4*)&x[gb];
    float4 o4;
    o4.x = fmaf(sca[u * 4 + 0], o[0] + r2.x, x4.x);
    o4.y = fmaf(sca[u * 4 + 1], o[1] + r2.y, x4.y);
    o4.z = fmaf(sca[u * 4 + 2], o[2] + r2.z, x4.z);
    o4.w = fmaf(sca[u * 4 + 3], o[3] + r2.w, x4.w);
    *(float4*)&out[gb] = o4;
}

// ---------------------------------------------------------------------------
extern "C" void kernel_launch(void* const* d_in, const int* in_sizes, int n_in,
                              void* d_out, int out_size, void* d_ws, size_t ws_size,
                              hipStream_t stream) {
    const float* x     = (const float*)d_in[0];
    const float* Wq    = (const float*)d_in[1];
    const float* bq    = (const float*)d_in[2];
    const float* Wk    = (const float*)d_in[3];
    const float* bk    = (const float*)d_in[4];
    const float* Wv    = (const float*)d_in[5];
    const float* bv    = (const float*)d_in[6];
    const float* gamma = (const float*)d_in[7];
    float* out = (float*)d_out;

    char* wsb = (char*)d_ws;
    unsigned short* qT = (unsigned short*)(wsb + OFF_QT);
    unsigned short* kT = (unsigned short*)(wsb + OFF_KT);
    unsigned short* vP = (unsigned short*)(wsb + OFF_VP);
    unsigned short* xT = (unsigned short*)(wsb + OFF_XT);
    unsigned short* wb = (unsigned short*)(wsb + OFF_WB);

    cvtT<<<dim3(457), 256, 0, stream>>>(x, Wq, Wk, Wv, xT, wb);
    qkv_ks<<<dim3(1312), 256, 0, stream>>>(xT, wb, bq, bk, bv, qT, kT, vP);
    attn7<<<dim3(36, 8), 512, 0, stream>>>(qT, kT, vP, x, gamma, out);
}

// Round 7
// 91.048 us; speedup vs baseline: 1.1424x; 1.1308x over previous
//
#include <hip/hip_runtime.h>

// Problem constants
#define HW   576      // 24*24 pixels
#define CC   512      // channels
#define NP   576      // unique key pixels (reflection dedup: kT[p]=K[smap(p)])

typedef float f32x4 __attribute__((ext_vector_type(4)));
typedef short s16x8 __attribute__((ext_vector_type(8)));

__device__ __forceinline__ unsigned short f2bf(float f) {
    unsigned u = __float_as_uint(f);                      // RNE fp32->bf16
    return (unsigned short)((u + 0x7FFFu + ((u >> 16) & 1u)) >> 16);
}
__device__ __forceinline__ float bf2f(unsigned short h) {
    return __uint_as_float((unsigned)h << 16);
}
// combined reflection multiplicity, separable axis factor:
// m[s] = min(s+4, 27-s, 7) + (1<=s<=3 ? 4-s : 0) + (20<=s<=22 ? s-19 : 0)
__device__ __forceinline__ float maxis(int s) {
    int c = s + 4; if (27 - s < c) c = 27 - s; if (c > 7) c = 7;
    if (s >= 1 && s <= 3)  c += 4 - s;
    if (s >= 20 && s <= 22) c += s - 19;
    return (float)c;
}

// Workspace byte offsets (total ~3.93 MB)
#define OFF_QT 0u         // bf16 [8][576][64]
#define OFF_KT 589824u    // bf16 [8][576][64]
#define OFF_VP 1179648u   // bf16 [8][64][576]
#define OFF_XT 1769472u   // bf16 [576][512]
#define OFF_WB 2359296u   // bf16 [3][512][512]

// ---------------------------------------------------------------------------
// Kernel 0: build xT (bf16 transpose of x, LDS-tiled 64x64) and wb (bf16
// copy of Wq/Wk/Wv). grid 456 blocks x 256. (Zero pad row no longer needed:
// reflection dedup removed all pad-position rows.)
// ---------------------------------------------------------------------------
__global__ __launch_bounds__(256) void cvtT(
    const float* __restrict__ x,
    const float* __restrict__ Wq, const float* __restrict__ Wk,
    const float* __restrict__ Wv,
    unsigned short* __restrict__ xT, unsigned short* __restrict__ wb)
{
    const int b = blockIdx.x, t = threadIdx.x;
    if (b < 72) {                                  // transpose: 9 pix-tiles x 8 chan-tiles
        __shared__ float tile[64][65];             // [chan][pix]; stride 65 -> 2-way free
        const int pt = b % 9, ct = b / 9;
        const int p0 = pt * 64, c0 = ct * 64;
        const int tr = t >> 4, tc4 = (t & 15) * 4;
        #pragma unroll
        for (int cr = 0; cr < 4; ++cr) {
            const int row = cr * 16 + tr;          // chan_local
            const float4 v = *(const float4*)&x[(size_t)(c0 + row) * HW + p0 + tc4];
            tile[row][tc4 + 0] = v.x;
            tile[row][tc4 + 1] = v.y;
            tile[row][tc4 + 2] = v.z;
            tile[row][tc4 + 3] = v.w;
        }
        __syncthreads();
        #pragma unroll
        for (int cr = 0; cr < 4; ++cr) {
            const int prow = cr * 16 + tr;         // pix_local
            ushort4 o;
            o.x = f2bf(tile[tc4 + 0][prow]);
            o.y = f2bf(tile[tc4 + 1][prow]);
            o.z = f2bf(tile[tc4 + 2][prow]);
            o.w = f2bf(tile[tc4 + 3][prow]);
            *(ushort4*)&xT[(size_t)(p0 + prow) * CC + c0 + tc4] = o;
        }
    } else {                                       // W convert: 384 blocks x 2048 elems
        const int wi = (b - 72) * 2048 + t * 8;
        const int sel = wi >> 18, off = wi & 262143;
        const float* src = (sel == 0) ? Wq : (sel == 1) ? Wk : Wv;
        const float4 v0 = *(const float4*)&src[off];
        const float4 v1 = *(const float4*)&src[off + 4];
        ushort4 o0, o1;
        o0.x = f2bf(v0.x); o0.y = f2bf(v0.y); o0.z = f2bf(v0.z); o0.w = f2bf(v0.w);
        o1.x = f2bf(v1.x); o1.y = f2bf(v1.y); o1.z = f2bf(v1.z); o1.w = f2bf(v1.w);
        *(ushort4*)&wb[wi]     = o0;
        *(ushort4*)&wb[wi + 4] = o1;
    }
}

// ---------------------------------------------------------------------------
// Kernel 1: Q/K/V projections, K-split MFMA. One BLOCK = one 32x32 output
// tile; the block's 4 waves each cover K-range [w*128, w*128+128), then a
// one-barrier LDS f32x4 reduce: wave w sums and stores 16x16 sub-tile w.
// 864 blocks x 256 (was 1312: K/V shrank to 576 unique pixel rows, and all
// smapf reflection indirection is gone — plain rows everywhere).
//   b <  288: D[pix 576][chan]  -> qT [head][pix][64]
//   b <  576: D[pix 576][chan]  -> kT [head][pix][64]
//   else    : D[chan][pix 576]  -> vP [head][64][576]
// ---------------------------------------------------------------------------
__global__ __launch_bounds__(256) void qkv_ks(
    const unsigned short* __restrict__ xT, const unsigned short* __restrict__ wb,
    const float* __restrict__ bq, const float* __restrict__ bk,
    const float* __restrict__ bv,
    unsigned short* __restrict__ qT, unsigned short* __restrict__ kT,
    unsigned short* __restrict__ vP)
{
    const int b = blockIdx.x;
    const int t = threadIdx.x;
    const int lane = t & 63, w = t >> 6;
    const int fr = lane & 15, u = lane >> 4;

    int sel, m0, n0;
    if (b < 288)      { sel = 0; m0 = (b >> 4) << 5;               n0 = (b & 15) << 5; }
    else if (b < 576) { const int k = b - 288; sel = 1; m0 = (k >> 4) << 5; n0 = (k & 15) << 5; }
    else              { const int k = b - 576; sel = 2; m0 = (k & 15) << 5; n0 = (k >> 4) << 5; }

    const unsigned short *A, *B;
    if (sel == 0)      { A = xT;          B = wb; }
    else if (sel == 1) { A = xT;          B = wb + 262144; }
    else               { A = wb + 524288; B = xT; }

    const int kw = w * 128;                       // this wave's K-range
    const unsigned short* Ap0 = A + (size_t)(m0 + fr)      * CC + kw + u * 8;
    const unsigned short* Ap1 = A + (size_t)(m0 + 16 + fr) * CC + kw + u * 8;
    const unsigned short* Bp0 = B + (size_t)(n0 + fr)      * CC + kw + u * 8;
    const unsigned short* Bp1 = B + (size_t)(n0 + 16 + fr) * CC + kw + u * 8;

    f32x4 acc00 = (f32x4){0.f, 0.f, 0.f, 0.f};
    f32x4 acc01 = (f32x4){0.f, 0.f, 0.f, 0.f};
    f32x4 acc10 = (f32x4){0.f, 0.f, 0.f, 0.f};
    f32x4 acc11 = (f32x4){0.f, 0.f, 0.f, 0.f};
    #pragma unroll
    for (int k0 = 0; k0 < 128; k0 += 32) {
        const s16x8 a0 = *(const s16x8*)(Ap0 + k0);
        const s16x8 a1 = *(const s16x8*)(Ap1 + k0);
        const s16x8 b0 = *(const s16x8*)(Bp0 + k0);
        const s16x8 b1 = *(const s16x8*)(Bp1 + k0);
        acc00 = __builtin_amdgcn_mfma_f32_16x16x32_bf16(a0, b0, acc00, 0, 0, 0);
        acc01 = __builtin_amdgcn_mfma_f32_16x16x32_bf16(a0, b1, acc01, 0, 0, 0);
        acc10 = __builtin_amdgcn_mfma_f32_16x16x32_bf16(a1, b0, acc10, 0, 0, 0);
        acc11 = __builtin_amdgcn_mfma_f32_16x16x32_bf16(a1, b1, acc11, 0, 0, 0);
    }

    // cross-wave K-reduce in LDS; wave w owns sub-tile (mi=w>>1, ni=w&1)
    __shared__ __align__(16) f32x4 red[4][4][64];  // [wave][subtile][lane]
    red[w][0][lane] = acc00;
    red[w][1][lane] = acc01;
    red[w][2][lane] = acc10;
    red[w][3][lane] = acc11;
    __syncthreads();

    f32x4 v = red[0][w][lane];
    #pragma unroll
    for (int w2 = 1; w2 < 4; ++w2) v = v + red[w2][w][lane];

    // epilogue: C/D layout col(fr)=n, row(u*4+r)=m (within 16x16 sub-tile)
    const int mi = w >> 1, ni = w & 1;
    const int n = n0 + ni * 16 + fr;
    #pragma unroll
    for (int r = 0; r < 4; ++r) {
        const int m = m0 + mi * 16 + u * 4 + r;
        if (sel == 0) {
            qT[((size_t)(n >> 6) * HW + m) * 64 + (n & 63)] = f2bf(v[r] + bq[n]);
        } else if (sel == 1) {
            kT[((size_t)(n >> 6) * NP + m) * 64 + (n & 63)] = f2bf(v[r] + bk[n]);
        } else {
            vP[((size_t)(m >> 6) * 64 + (m & 63)) * NP + n] = f2bf(v[r] + bv[m]);
        }
    }
}

// ---------------------------------------------------------------------------
// Kernel 2: single-pass MFMA attention + epilogue, 8 waves, NO-MAX softmax,
// DEDUPLICATED keys: 576 unique pixels with combined multiplicity
// mult[src] = my[sy]*mx[sx] (sum of window counts over all reflected padded
// positions mapping to src). QK: 36 tiles split 5/4 across 8 waves; weights
// bf16 into Wl (stride 592 -> bank-step-8 pattern). PV: wave w owns (d-tile
// w&3, p-half w>>2: 288 p, 9 k-steps, dual acc). Two barriers, no fences,
// no cross-block traffic. Block writes out = gamma*O/l + x.
// ---------------------------------------------------------------------------
#define WLS 592       // Wl row stride (shorts); 592 % 64 == 16 -> bank step 8
__global__ __launch_bounds__(512) void attn8(
    const unsigned short* __restrict__ qT, const unsigned short* __restrict__ kT,
    const unsigned short* __restrict__ vP, const float* __restrict__ x,
    const float* __restrict__ gamma, float* __restrict__ out)
{
    const int q0 = blockIdx.x * 16;
    const int hd = blockIdx.y;
    const int t  = threadIdx.x;
    const int lane = t & 63, w = t >> 6;          // w in [0,8)
    const int fr = lane & 15, u = lane >> 4;

    __shared__ float mult_s[NP];                  // combined multiplicity
    __shared__ __align__(16) unsigned short Wl[16 * WLS];  // weights [q][576p]
    __shared__ float lw[128], sca[16];
    __shared__ float4 red[4][64];                 // PV p-half partials

    // QK tile ownership: waves 0-3 own 5 tiles, 4-7 own 4 (36 total)
    const int ntw = (w < 4) ? 5 : 4;
    const int off = (w < 4) ? w * 80 : 320 + (w - 4) * 64;
    const int sz  = ntw * 16;

    // wave-local mult fill: wave w writes/reads ONLY its own slice -> no barrier
    #pragma unroll
    for (int j = 0; j < 2; ++j) {
        const int li = j * 64 + lane;
        if (li < sz) {
            const int i = off + li;
            const int sy = i / 24, sx = i - sy * 24;
            mult_s[i] = maxis(sy) * maxis(sx);
        }
    }

    // q B-frags (shared across this wave's p-tiles)
    const unsigned short* qrow = qT + ((size_t)hd * HW + q0 + fr) * 64 + u * 8;
    const s16x8 b0 = *(const s16x8*)qrow;
    const s16x8 b1 = *(const s16x8*)(qrow + 32);

    // QK: ntw E^T tiles (16p x 16q) per wave
    f32x4 e[5];
    #pragma unroll
    for (int t4 = 0; t4 < 5; ++t4) {
        if (t4 < ntw) {
            const unsigned short* krow =
                kT + ((size_t)hd * NP + off + t4 * 16 + fr) * 64 + u * 8;
            const s16x8 a0 = *(const s16x8*)krow;
            const s16x8 a1 = *(const s16x8*)(krow + 32);
            f32x4 a = (f32x4){0.f, 0.f, 0.f, 0.f};
            a = __builtin_amdgcn_mfma_f32_16x16x32_bf16(a0, b0, a, 0, 0, 0);
            a = __builtin_amdgcn_mfma_f32_16x16x32_bf16(a1, b1, a, 0, 0, 0);
            e[t4] = a;
        }
    }

    // weights = mult * exp(e) (no max shift — bounded energies); bf16 into Wl
    float sum = 0.f;
    #pragma unroll
    for (int t4 = 0; t4 < 5; ++t4) {
        if (t4 < ntw) {
            const float4 c4 = *(const float4*)&mult_s[off + t4 * 16 + u * 4];
            const float cw[4] = {c4.x, c4.y, c4.z, c4.w};
            unsigned short wb4[4];
            #pragma unroll
            for (int r = 0; r < 4; ++r) {
                const float wv2 = cw[r] * __expf(e[t4][r]);
                sum += wv2;
                wb4[r] = f2bf(wv2);
            }
            const int ho = fr * WLS + off + t4 * 16 + u * 4;
            *(unsigned*)&Wl[ho]     = (unsigned)wb4[0] | ((unsigned)wb4[1] << 16);
            *(unsigned*)&Wl[ho + 2] = (unsigned)wb4[2] | ((unsigned)wb4[3] << 16);
        }
    }
    sum += __shfl_xor(sum, 16);
    sum += __shfl_xor(sum, 32);
    if (lane < 16) lw[w * 16 + lane] = sum;
    __syncthreads();                              // Wl + lw complete

    if (t < 16) {                                 // per-q scale = gamma / l
        float lq = 0.f;
        #pragma unroll
        for (int j = 0; j < 8; ++j) lq += lw[j * 16 + t];
        sca[t] = gamma[0] / lq;
    }

    // PV: wave w owns (d-tile w&3, p-half w>>2); O[16q][16d] over 288 p.
    // Dual accumulators (parity) break the dependent MFMA chain.
    const int dt = w & 3, ph = w >> 2;
    const int poff = ph * 288;
    f32x4 oA = (f32x4){0.f, 0.f, 0.f, 0.f};
    f32x4 oB = (f32x4){0.f, 0.f, 0.f, 0.f};
    const unsigned short* vrow =
        vP + ((size_t)hd * 64 + dt * 16 + fr) * NP + poff + u * 8;
    const unsigned short* wrow = &Wl[fr * WLS + poff + u * 8];
    #pragma unroll
    for (int c = 0; c < 9; ++c) {
        const s16x8 aw = *(const s16x8*)(wrow + c * 32);
        const s16x8 bv2 = *(const s16x8*)(vrow + c * 32);
        if (c & 1) oB = __builtin_amdgcn_mfma_f32_16x16x32_bf16(aw, bv2, oB, 0, 0, 0);
        else       oA = __builtin_amdgcn_mfma_f32_16x16x32_bf16(aw, bv2, oA, 0, 0, 0);
    }
    const f32x4 o = oA + oB;
    if (w >= 4) red[dt][lane] = (float4){o[0], o[1], o[2], o[3]};
    __syncthreads();                              // red + sca ready
    if (w >= 4) return;

    // epilogue: C layout row=q (u*4+r), col=d (dt*16+fr); each lane stores a
    // float4 run of 4 consecutive q at row d -> 16B coalesced segments.
    const float4 r2 = red[dt][lane];
    const int d = hd * 64 + dt * 16 + fr;
    const size_t gb = (size_t)d * HW + q0 + u * 4;
    const float4 x4 = *(const float4*)&x[gb];
    float4 o4;
    o4.x = fmaf(sca[u * 4 + 0], o[0] + r2.x, x4.x);
    o4.y = fmaf(sca[u * 4 + 1], o[1] + r2.y, x4.y);
    o4.z = fmaf(sca[u * 4 + 2], o[2] + r2.z, x4.z);
    o4.w = fmaf(sca[u * 4 + 3], o[3] + r2.w, x4.w);
    *(float4*)&out[gb] = o4;
}

// ---------------------------------------------------------------------------
extern "C" void kernel_launch(void* const* d_in, const int* in_sizes, int n_in,
                              void* d_out, int out_size, void* d_ws, size_t ws_size,
                              hipStream_t stream) {
    const float* x     = (const float*)d_in[0];
    const float* Wq    = (const float*)d_in[1];
    const float* bq    = (const float*)d_in[2];
    const float* Wk    = (const float*)d_in[3];
    const float* bk    = (const float*)d_in[4];
    const float* Wv    = (const float*)d_in[5];
    const float* bv    = (const float*)d_in[6];
    const float* gamma = (const float*)d_in[7];
    float* out = (float*)d_out;

    char* wsb = (char*)d_ws;
    unsigned short* qT = (unsigned short*)(wsb + OFF_QT);
    unsigned short* kT = (unsigned short*)(wsb + OFF_KT);
    unsigned short* vP = (unsigned short*)(wsb + OFF_VP);
    unsigned short* xT = (unsigned short*)(wsb + OFF_XT);
    unsigned short* wb = (unsigned short*)(wsb + OFF_WB);

    cvtT<<<dim3(456), 256, 0, stream>>>(x, Wq, Wk, Wv, xT, wb);
    qkv_ks<<<dim3(864), 256, 0, stream>>>(xT, wb, bq, bk, bv, qT, kT, vP);
    attn8<<<dim3(36, 8), 512, 0, stream>>>(qT, kT, vP, x, gamma, out);
}